// Round 15
// baseline (95.629 us; speedup 1.0000x reference)
//
#include <hip/hip_runtime.h>
#include <hip/hip_bf16.h>

typedef __hip_bfloat16 bf16;
typedef __attribute__((ext_vector_type(8))) short bf16x8;
typedef __attribute__((ext_vector_type(4))) float f32x4;

#define NBATCH 16
#define CCH    512
#define PP     1024
#define OCH    64

__device__ __forceinline__ void gload16(const void* g, void* l) {
  __builtin_amdgcn_global_load_lds(
      (const __attribute__((address_space(1))) void*)g,
      (__attribute__((address_space(3))) void*)l, 16, 0, 0);
}
__device__ __forceinline__ float bf2f(bf16 v) { return __bfloat162float(v); }
__device__ __forceinline__ bf16  f2bf(float v) { return __float2bfloat16(v); }

__device__ __forceinline__ void barrier_vm0() {
  asm volatile("s_waitcnt vmcnt(0)" ::: "memory");
  __builtin_amdgcn_s_barrier();
  asm volatile("" ::: "memory");
}
__device__ __forceinline__ void barrier_lgkm0() {
  asm volatile("s_waitcnt lgkmcnt(0)" ::: "memory");
  __builtin_amdgcn_s_barrier();
  asm volatile("" ::: "memory");
}

// ---------------------------------------------------------- weight prep (small)
__global__ void prep_kernel(const float* __restrict__ key_w, const float* __restrict__ key_b,
                            const float* __restrict__ query_w, const float* __restrict__ query_b,
                            const float* __restrict__ value_w, const float* __restrict__ value_b,
                            bf16* __restrict__ wqk_hi, bf16* __restrict__ wqk_lo,
                            bf16* __restrict__ wv, float* __restrict__ bias_qk,
                            float* __restrict__ bias_v) {
  const int t = blockIdx.x * blockDim.x + threadIdx.x;
  const int TOT_QK = 128 * 512;
  const int TOT_V  = 512 * 512;
  if (t < TOT_QK) {
    const int m = t >> 9, c = t & 511;
    const float v = (m < 64) ? query_w[m * 512 + c] : key_w[(m - 64) * 512 + c];
    const bf16 hi = f2bf(v);
    wqk_hi[t] = hi;
    wqk_lo[t] = f2bf(v - bf2f(hi));
  } else if (t < TOT_QK + TOT_V) {
    const int u = t - TOT_QK;
    wv[u] = f2bf(value_w[u]);
  } else if (t < TOT_QK + TOT_V + 128) {
    const int m = t - (TOT_QK + TOT_V);
    bias_qk[m] = (m < 64) ? query_b[m] : key_b[m - 64];
  } else if (t < TOT_QK + TOT_V + 128 + 512) {
    const int m = t - (TOT_QK + TOT_V + 128);
    bias_v[m] = value_b[m];
  }
}

// ---------------- merged QKV projection GEMM with IN-KERNEL transpose of x ----
// B-operand built per K-step: x tile staged fp32 untransposed (gload16, linear),
// columns pulled to registers, converted to bf16 hi/lo, written as swizzled B
// tiles (pu = chunk ^ (row&7)). blocks [0,128): qk path (3-term hi/lo, M=128).
// blocks [128,384): v path, M=256 per block — TWO m-tiles share one x-stage +
// transpose (eliminates the 4x redundant transpose of R14's 4-blocks-per-xtile).
__global__ __launch_bounds__(256) void gemm_qkv_kernel(
    const bf16* __restrict__ Whi, const bf16* __restrict__ Wlo,
    const bf16* __restrict__ Wv, const float* __restrict__ x,
    const float* __restrict__ biasqk, const float* __restrict__ biasv,
    bf16* __restrict__ qhi, bf16* __restrict__ qlo,
    bf16* __restrict__ khi, bf16* __restrict__ klo,
    bf16* __restrict__ Vout) {
  // sm: A tiles [0,32K) (qk: hi 16K + lo 16K; v: m-tile0 16K + m-tile1 16K).
  // union [32K,64K): Xs fp32 [64][128] staged, then Bsh(16K)+Bsl(16K).
  __shared__ __align__(16) char sm[65536];
  const int tid = threadIdx.x, l = tid & 63, w = tid >> 6;
  const int li = l & 15, g = l >> 4;
  const int lrow = l >> 3, lcol = (l & 7) * 8, wr = w >> 1, wc = w & 1;
  const int tp = tid >> 1;           // transpose role: p-column 0..127
  const int tch = (tid & 1) * 32;    // transpose role: c-half base
  const f32x4 z = {0.f, 0.f, 0.f, 0.f};
  f32x4 acc[4][4];
#pragma unroll
  for (int i = 0; i < 4; ++i)
#pragma unroll
    for (int j = 0; j < 4; ++j) acc[i][j] = z;

  char* Xs  = sm + 32768;
  char* Bsh = sm + 32768;
  char* Bsl = sm + 49152;

  if (blockIdx.x < 128) {
    // ---------------- qk path
    const int id = blockIdx.x;
    const int n0 = (id & 7) * 128, bn = id >> 3;
    const float* xb = x + (size_t)bn * CCH * PP;
    bf16* Ash = (bf16*)sm;
    bf16* Asl = (bf16*)(sm + 16384);

    for (int kt = 0; kt < CCH; kt += 64) {
#pragma unroll
      for (int it = 0; it < 4; ++it) {
        const int chunk = w * 4 + it;
        const int ar = chunk * 8 + lrow;
        gload16(Whi + (size_t)ar * CCH + kt + lcol, &Ash[chunk * 512]);
        gload16(Wlo + (size_t)ar * CCH + kt + lcol, &Asl[chunk * 512]);
      }
#pragma unroll
      for (int i = 0; i < 8; ++i) {
        const int s = i * 256 + w * 64 + l;
        const int row = s >> 5, col16 = s & 31;
        gload16(xb + (size_t)(kt + row) * PP + n0 + col16 * 4,
                Xs + (i * 256 + w * 64) * 16);
      }
      __syncthreads();

      float f[32];
#pragma unroll
      for (int k = 0; k < 32; ++k)
        f[k] = *(const float*)(Xs + (size_t)(tch + k) * 512 + tp * 4);
      barrier_lgkm0();  // all column reads done before Bs overwrites Xs
#pragma unroll
      for (int k2 = 0; k2 < 4; ++k2) {
        bf16x8 hv, lv;
#pragma unroll
        for (int j = 0; j < 8; ++j) {
          const float ff = f[k2 * 8 + j];
          const bf16 h = f2bf(ff);
          const bf16 lo_ = f2bf(ff - bf2f(h));
          short hs, ls;
          __builtin_memcpy(&hs, &h, 2);
          __builtin_memcpy(&ls, &lo_, 2);
          hv[j] = hs;
          lv[j] = ls;
        }
        const int chunk = (tch >> 3) + k2;
        const int pu = chunk ^ (tp & 7);
        *(bf16x8*)(Bsh + tp * 128 + pu * 16) = hv;
        *(bf16x8*)(Bsl + tp * 128 + pu * 16) = lv;
      }
      barrier_lgkm0();  // B tiles visible

#pragma unroll
      for (int kk = 0; kk < 2; ++kk) {
        bf16x8 ah[4], al[4], bh[4], bl[4];
        const int ko = kk * 32 + g * 8;
#pragma unroll
        for (int i = 0; i < 4; ++i) {
          const int r = (wr * 64 + i * 16 + li) * 64 + ko;
          ah[i] = *(const bf16x8*)&Ash[r];
          al[i] = *(const bf16x8*)&Asl[r];
        }
#pragma unroll
        for (int j = 0; j < 4; ++j) {
          const int row = wc * 64 + j * 16 + li;
          const int pu = (4 * kk + g) ^ (row & 7);
          bh[j] = *(const bf16x8*)(Bsh + row * 128 + pu * 16);
          bl[j] = *(const bf16x8*)(Bsl + row * 128 + pu * 16);
        }
#pragma unroll
        for (int i = 0; i < 4; ++i)
#pragma unroll
          for (int j = 0; j < 4; ++j) {
            acc[i][j] = __builtin_amdgcn_mfma_f32_16x16x32_bf16(ah[i], bh[j], acc[i][j], 0, 0, 0);
            acc[i][j] = __builtin_amdgcn_mfma_f32_16x16x32_bf16(ah[i], bl[j], acc[i][j], 0, 0, 0);
            acc[i][j] = __builtin_amdgcn_mfma_f32_16x16x32_bf16(al[i], bh[j], acc[i][j], 0, 0, 0);
          }
      }
      __syncthreads();  // fragment reads done before next-step staging overwrites
    }
    const size_t qoff = (size_t)bn * PP * OCH;
#pragma unroll
    for (int i = 0; i < 4; ++i)
#pragma unroll
      for (int j = 0; j < 4; ++j)
#pragma unroll
        for (int r = 0; r < 4; ++r) {
          const int m = wr * 64 + i * 16 + g * 4 + r;
          const int p = n0 + wc * 64 + j * 16 + li;
          const float v = acc[i][j][r] + biasqk[m];
          const bf16 hi = f2bf(v);
          const bf16 lo = f2bf(v - bf2f(hi));
          if (m < 64) {
            qhi[qoff + (size_t)p * OCH + m] = hi;
            qlo[qoff + (size_t)p * OCH + m] = lo;
          } else {
            khi[qoff + (size_t)p * OCH + (m - 64)] = hi;
            klo[qoff + (size_t)p * OCH + (m - 64)] = lo;
          }
        }
  } else {
    // ---------------- v path (hi-only B), M=256: 2 m-tiles share one transpose
    const int id = blockIdx.x - 128;                 // 0..255
    const int n0 = (id & 7) * 128, m0 = ((id >> 3) & 1) * 256, bn = id >> 4;
    const float* xb = x + (size_t)bn * CCH * PP;
    bf16* As0 = (bf16*)sm;
    bf16* As1 = (bf16*)(sm + 16384);

    f32x4 acc1[4][4];
#pragma unroll
    for (int i = 0; i < 4; ++i)
#pragma unroll
      for (int j = 0; j < 4; ++j) acc1[i][j] = z;

    for (int kt = 0; kt < CCH; kt += 64) {
#pragma unroll
      for (int it = 0; it < 4; ++it) {
        const int chunk = w * 4 + it;
        const int ar = chunk * 8 + lrow;
        gload16(Wv + (size_t)(m0 + ar) * CCH + kt + lcol, &As0[chunk * 512]);
        gload16(Wv + (size_t)(m0 + 128 + ar) * CCH + kt + lcol, &As1[chunk * 512]);
      }
#pragma unroll
      for (int i = 0; i < 8; ++i) {
        const int s = i * 256 + w * 64 + l;
        const int row = s >> 5, col16 = s & 31;
        gload16(xb + (size_t)(kt + row) * PP + n0 + col16 * 4,
                Xs + (i * 256 + w * 64) * 16);
      }
      __syncthreads();

      float f[32];
#pragma unroll
      for (int k = 0; k < 32; ++k)
        f[k] = *(const float*)(Xs + (size_t)(tch + k) * 512 + tp * 4);
      barrier_lgkm0();
#pragma unroll
      for (int k2 = 0; k2 < 4; ++k2) {
        bf16x8 hv;
#pragma unroll
        for (int j = 0; j < 8; ++j) {
          const bf16 h = f2bf(f[k2 * 8 + j]);
          short hs;
          __builtin_memcpy(&hs, &h, 2);
          hv[j] = hs;
        }
        const int chunk = (tch >> 3) + k2;
        const int pu = chunk ^ (tp & 7);
        *(bf16x8*)(Bsh + tp * 128 + pu * 16) = hv;
      }
      barrier_lgkm0();

#pragma unroll
      for (int kk = 0; kk < 2; ++kk) {
        bf16x8 a0[4], a1[4], b[4];
        const int ko = kk * 32 + g * 8;
#pragma unroll
        for (int i = 0; i < 4; ++i) {
          a0[i] = *(const bf16x8*)&As0[(wr * 64 + i * 16 + li) * 64 + ko];
          a1[i] = *(const bf16x8*)&As1[(wr * 64 + i * 16 + li) * 64 + ko];
        }
#pragma unroll
        for (int j = 0; j < 4; ++j) {
          const int row = wc * 64 + j * 16 + li;
          const int pu = (4 * kk + g) ^ (row & 7);
          b[j] = *(const bf16x8*)(Bsh + row * 128 + pu * 16);
        }
#pragma unroll
        for (int i = 0; i < 4; ++i)
#pragma unroll
          for (int j = 0; j < 4; ++j) {
            acc[i][j]  = __builtin_amdgcn_mfma_f32_16x16x32_bf16(a0[i], b[j], acc[i][j], 0, 0, 0);
            acc1[i][j] = __builtin_amdgcn_mfma_f32_16x16x32_bf16(a1[i], b[j], acc1[i][j], 0, 0, 0);
          }
      }
      __syncthreads();
    }
#pragma unroll
    for (int i = 0; i < 4; ++i)
#pragma unroll
      for (int j = 0; j < 4; ++j)
#pragma unroll
        for (int r = 0; r < 4; ++r) {
          const int m = m0 + wr * 64 + i * 16 + g * 4 + r;
          const int p = n0 + wc * 64 + j * 16 + li;
          Vout[(size_t)bn * CCH * PP + (size_t)m * PP + p] = f2bf(acc[i][j][r] + biasv[m]);
          Vout[(size_t)bn * CCH * PP + (size_t)(m + 128) * PP + p] = f2bf(acc1[i][j][r] + biasv[m + 128]);
        }
  }
}

// ---------------------------------------------------- fused flash attention + epilogue
// R7/R13 structure FROZEN (best measured). Unchanged.
#define KT 32
#define NT 32

__global__ __launch_bounds__(512, 2) void fused_attn_kernel(
    const bf16* __restrict__ qhi, const bf16* __restrict__ qlo,
    const bf16* __restrict__ khi, const bf16* __restrict__ klo,
    const bf16* __restrict__ vbuf, const float* __restrict__ tensor,
    const float* __restrict__ gamma, float* __restrict__ out) {
  __shared__ __align__(16) char smem[102400];
  __shared__ float red[128];
  __shared__ float fq[64];
  const int tid = threadIdx.x, l = tid & 63, w = tid >> 6;

  const int d = blockIdx.x;
  const int idx = d >> 3;
  const int bn = (d & 7) * 2 + (idx >> 4);
  const int qt0 = (idx & 15) * 64;

  const size_t qkoff = (size_t)bn * PP * OCH;
  const size_t voff  = (size_t)bn * CCH * PP;
  char* Qh = smem;
  char* Ql = smem + 8192;
  char* Pb = smem + 98304;

  {
    const int s = (w << 6) | l;
    const int row = s >> 3, pu = s & 7, lu = pu ^ (row & 7);
    const size_t src = qkoff + (size_t)(qt0 + row) * OCH + lu * 8;
    gload16(qhi + src, Qh + w * 1024);
    gload16(qlo + src, Ql + w * 1024);
  }
  barrier_vm0();

  bf16x8 ah[2], al[2];
  {
    const int qrow = ((w & 3) << 4) + (l & 15);
#pragma unroll
    for (int h = 0; h < 2; ++h) {
      const int lu = (l >> 4) + 4 * h, pu = lu ^ (qrow & 7);
      ah[h] = *(const bf16x8*)(Qh + qrow * 128 + pu * 16);
      al[h] = *(const bf16x8*)(Ql + qrow * 128 + pu * 16);
    }
  }

  auto stage_kv = [&](int t, char* khD, char* klD, char* vD) {
    {
      const int s = ((w & 3) << 6) | l;
      const int row = s >> 3, pu = s & 7, lu = pu ^ (row & 7);
      const bf16* srcp = ((w < 4) ? khi : klo) + qkoff + (size_t)(t * KT + row) * OCH + lu * 8;
      gload16(srcp, ((w < 4) ? khD : klD) + (w & 3) * 1024);
    }
#pragma unroll
    for (int c4 = 0; c4 < 4; ++c4) {
      const int s = (w << 8) + (c4 << 6) + l;
      const int row = s >> 2, pu = s & 3, lu = pu ^ ((row >> 1) & 3);
      const bf16* srcp = vbuf + voff + (size_t)row * PP + t * KT + lu * 8;
      gload16(srcp, vD + ((w << 8) + (c4 << 6)) * 16);
    }
  };

  stage_kv(0, smem + 16384, smem + 24576, smem + 32768);

  f32x4 acc[4][4];
  const f32x4 z = {0.f, 0.f, 0.f, 0.f};
#pragma unroll
  for (int i = 0; i < 4; ++i)
#pragma unroll
    for (int j = 0; j < 4; ++j) acc[i][j] = z;
  float psum[4] = {0.f, 0.f, 0.f, 0.f};
  const int kf = w >> 2;

  for (int t = 0; t < NT; ++t) {
    char* khB = smem + 16384 + ((t & 1) ? 4096 : 0);
    char* klB = smem + 24576 + ((t & 1) ? 4096 : 0);
    char* vB  = smem + 32768 + ((t & 1) ? 32768 : 0);

    barrier_vm0();

    if (t + 1 < NT) {
      stage_kv(t + 1,
               smem + 16384 + ((t & 1) ? 0 : 4096),
               smem + 24576 + ((t & 1) ? 0 : 4096),
               smem + 32768 + ((t & 1) ? 0 : 32768));
    }

    bf16x8 kh_[2], kl_[2];
    const int krow = (kf << 4) + (l & 15);
#pragma unroll
    for (int h = 0; h < 2; ++h) {
      const int lu = (l >> 4) + 4 * h, pu = lu ^ (krow & 7);
      kh_[h] = *(const bf16x8*)(khB + krow * 128 + pu * 16);
      kl_[h] = *(const bf16x8*)(klB + krow * 128 + pu * 16);
    }
    __builtin_amdgcn_s_setprio(1);
    f32x4 s = z;
    s = __builtin_amdgcn_mfma_f32_16x16x32_bf16(ah[0], kh_[0], s, 0, 0, 0);
    s = __builtin_amdgcn_mfma_f32_16x16x32_bf16(ah[1], kh_[1], s, 0, 0, 0);
    s = __builtin_amdgcn_mfma_f32_16x16x32_bf16(al[0], kh_[0], s, 0, 0, 0);
    s = __builtin_amdgcn_mfma_f32_16x16x32_bf16(al[1], kh_[1], s, 0, 0, 0);
    s = __builtin_amdgcn_mfma_f32_16x16x32_bf16(ah[0], kl_[0], s, 0, 0, 0);
    s = __builtin_amdgcn_mfma_f32_16x16x32_bf16(ah[1], kl_[1], s, 0, 0, 0);
    __builtin_amdgcn_s_setprio(0);

#pragma unroll
    for (int r = 0; r < 4; ++r) {
      const float pv = __expf(s[r] - 30.f);
      const bf16 pb16 = f2bf(pv);
      psum[r] += bf2f(pb16);
      const int q = ((w & 3) << 4) + ((l >> 4) << 2) + r;
      const int k = (kf << 4) + (l & 15);
      const int pu = (k >> 3) ^ ((q >> 1) & 3);
      *(bf16*)(Pb + q * 64 + pu * 16 + (k & 7) * 2) = pb16;
    }
    barrier_lgkm0();

    bf16x8 va[4], pb[4];
#pragma unroll
    for (int i = 0; i < 4; ++i) {
      const int crow = (w << 6) + (i << 4) + (l & 15);
      const int pu = (l >> 4) ^ ((crow >> 1) & 3);
      va[i] = *(const bf16x8*)(vB + crow * 64 + pu * 16);
    }
#pragma unroll
    for (int j = 0; j < 4; ++j) {
      const int prow = (j << 4) + (l & 15);
      const int pu = (l >> 4) ^ ((prow >> 1) & 3);
      pb[j] = *(const bf16x8*)(Pb + prow * 64 + pu * 16);
    }
    __builtin_amdgcn_s_setprio(1);
#pragma unroll
    for (int i = 0; i < 4; ++i)
#pragma unroll
      for (int j = 0; j < 4; ++j)
        acc[i][j] = __builtin_amdgcn_mfma_f32_16x16x32_bf16(va[i], pb[j], acc[i][j], 0, 0, 0);
    __builtin_amdgcn_s_setprio(0);
  }

  f32x4 tv0[8];
#pragma unroll
  for (int it = 0; it < 8; ++it) {
    const int chunk = it * 512 + tid;
    const int cl = chunk >> 4, ch = chunk & 15;
    tv0[it] = *(const f32x4*)&tensor[((size_t)bn * CCH + cl) * PP + qt0 + ch * 4];
  }

#pragma unroll
  for (int off = 1; off < 16; off <<= 1)
#pragma unroll
    for (int r = 0; r < 4; ++r) psum[r] += __shfl_xor(psum[r], off);
  if ((l & 15) == 0) {
#pragma unroll
    for (int r = 0; r < 4; ++r) {
      const int q = ((w & 3) << 4) + ((l >> 4) << 2) + r;
      red[q * 2 + kf] = psum[r];
    }
  }
  __syncthreads();
  if (tid < 64) fq[tid] = gamma[0] / (red[tid * 2] + red[tid * 2 + 1]);
  __syncthreads();

  float* rep = (float*)smem;
  for (int half = 0; half < 2; ++half) {
    if ((w >> 2) == half) {
#pragma unroll
      for (int i = 0; i < 4; ++i)
#pragma unroll
        for (int j = 0; j < 4; ++j) {
          const int q = (j << 4) + (l & 15);
          const float f = fq[q];
          const int c0 = ((w & 3) << 6) + (i << 4) + ((l >> 4) << 2);
#pragma unroll
          for (int r = 0; r < 4; ++r) rep[(c0 + r) * 68 + q] = acc[i][j][r] * f;
        }
    }
    __syncthreads();
#pragma unroll
    for (int it = 0; it < 8; ++it) {
      const int chunk = it * 512 + tid;
      const int cl = chunk >> 4, ch = chunk & 15;
      const size_t gi = ((size_t)bn * CCH + half * 256 + cl) * PP + qt0 + ch * 4;
      const f32x4 tv = (half == 0) ? tv0[it] : *(const f32x4*)&tensor[gi];
      const f32x4 rv = *(const f32x4*)&rep[cl * 68 + ch * 4];
      *(f32x4*)&out[gi] = tv + rv;
    }
    __syncthreads();
  }
}

// -------------------------------------------------------------------- launcher
extern "C" void kernel_launch(void* const* d_in, const int* in_sizes, int n_in,
                              void* d_out, int out_size, void* d_ws, size_t ws_size,
                              hipStream_t stream) {
  const float* tensor  = (const float*)d_in[0];
  const float* key_w   = (const float*)d_in[1];
  const float* key_b   = (const float*)d_in[2];
  const float* query_w = (const float*)d_in[3];
  const float* query_b = (const float*)d_in[4];
  const float* value_w = (const float*)d_in[5];
  const float* value_b = (const float*)d_in[6];
  const float* gamma   = (const float*)d_in[7];

  char* ws = (char*)d_ws;
  size_t off = 0;
  auto alloc = [&](size_t bytes) -> char* {
    char* p = ws + off;
    off += (bytes + 255) & ~(size_t)255;
    return p;
  };
  bf16* wqk_hi = (bf16*)alloc(128 * 512 * 2);
  bf16* wqk_lo = (bf16*)alloc(128 * 512 * 2);
  bf16* wv     = (bf16*)alloc(512 * 512 * 2);
  float* bias_qk = (float*)alloc(128 * 4);
  float* bias_v  = (float*)alloc(512 * 4);
  bf16* q_hi = (bf16*)alloc((size_t)NBATCH * PP * OCH * 2);
  bf16* q_lo = (bf16*)alloc((size_t)NBATCH * PP * OCH * 2);
  bf16* k_hi = (bf16*)alloc((size_t)NBATCH * PP * OCH * 2);
  bf16* k_lo = (bf16*)alloc((size_t)NBATCH * PP * OCH * 2);
  bf16* vbuf = (bf16*)alloc((size_t)NBATCH * CCH * PP * 2);
  (void)ws_size; (void)in_sizes; (void)n_in; (void)out_size;

  prep_kernel<<<dim3(1283), dim3(256), 0, stream>>>(
      key_w, key_b, query_w, query_b, value_w, value_b,
      wqk_hi, wqk_lo, wv, bias_qk, bias_v);

  gemm_qkv_kernel<<<dim3(384), dim3(256), 0, stream>>>(
      wqk_hi, wqk_lo, wv, tensor, bias_qk, bias_v,
      q_hi, q_lo, k_hi, k_lo, vbuf);

  fused_attn_kernel<<<dim3(256), dim3(512), 0, stream>>>(
      q_hi, q_lo, k_hi, k_lo, vbuf, tensor, gamma, (float*)d_out);
}

// Round 16
// 88.318 us; speedup vs baseline: 1.0828x; 1.0828x over previous
//
#include <hip/hip_runtime.h>
#include <hip/hip_bf16.h>

typedef __hip_bfloat16 bf16;
typedef __attribute__((ext_vector_type(8))) short bf16x8;
typedef __attribute__((ext_vector_type(4))) float f32x4;

#define NBATCH 16
#define CCH    512
#define PP     1024
#define OCH    64

__device__ __forceinline__ void gload16(const void* g, void* l) {
  __builtin_amdgcn_global_load_lds(
      (const __attribute__((address_space(1))) void*)g,
      (__attribute__((address_space(3))) void*)l, 16, 0, 0);
}
__device__ __forceinline__ float bf2f(bf16 v) { return __bfloat162float(v); }
__device__ __forceinline__ bf16  f2bf(float v) { return __float2bfloat16(v); }

__device__ __forceinline__ void barrier_vm0() {
  asm volatile("s_waitcnt vmcnt(0)" ::: "memory");
  __builtin_amdgcn_s_barrier();
  asm volatile("" ::: "memory");
}
__device__ __forceinline__ void barrier_lgkm0() {
  asm volatile("s_waitcnt lgkmcnt(0)" ::: "memory");
  __builtin_amdgcn_s_barrier();
  asm volatile("" ::: "memory");
}

// ---------------------------------------------------------- weight prep (small)
__global__ void prep_kernel(const float* __restrict__ key_w, const float* __restrict__ key_b,
                            const float* __restrict__ query_w, const float* __restrict__ query_b,
                            const float* __restrict__ value_w, const float* __restrict__ value_b,
                            bf16* __restrict__ wqk_hi, bf16* __restrict__ wqk_lo,
                            bf16* __restrict__ wv, float* __restrict__ bias_qk,
                            float* __restrict__ bias_v) {
  const int t = blockIdx.x * blockDim.x + threadIdx.x;
  const int TOT_QK = 128 * 512;
  const int TOT_V  = 512 * 512;
  if (t < TOT_QK) {
    const int m = t >> 9, c = t & 511;
    const float v = (m < 64) ? query_w[m * 512 + c] : key_w[(m - 64) * 512 + c];
    const bf16 hi = f2bf(v);
    wqk_hi[t] = hi;
    wqk_lo[t] = f2bf(v - bf2f(hi));
  } else if (t < TOT_QK + TOT_V) {
    const int u = t - TOT_QK;
    wv[u] = f2bf(value_w[u]);
  } else if (t < TOT_QK + TOT_V + 128) {
    const int m = t - (TOT_QK + TOT_V);
    bias_qk[m] = (m < 64) ? query_b[m] : key_b[m - 64];
  } else if (t < TOT_QK + TOT_V + 128 + 512) {
    const int m = t - (TOT_QK + TOT_V + 128);
    bias_v[m] = value_b[m];
  }
}

// ---------------- merged QKV projection GEMM with IN-KERNEL transpose of x ----
// R14 dataflow + X-staging software pipeline: X(t+1) issued before MFMA(t)
// (fire-and-forget gload16), counted vmcnt at step top waits only X(t) while
// W(t) stays in flight. B fragments pre-read to registers so the X region is
// free before the prefetch. blocks [0,128): qk (3-term hi/lo, M=128);
// blocks [128,640): v (bf16, M=128).
__global__ __launch_bounds__(256) void gemm_qkv_kernel(
    const bf16* __restrict__ Whi, const bf16* __restrict__ Wlo,
    const bf16* __restrict__ Wv, const float* __restrict__ x,
    const float* __restrict__ biasqk, const float* __restrict__ biasv,
    bf16* __restrict__ qhi, bf16* __restrict__ qlo,
    bf16* __restrict__ khi, bf16* __restrict__ klo,
    bf16* __restrict__ Vout) {
  // sm: A tiles [0,32K) (qk: hi 16K + lo 16K; v: hi 16K). union [32K,64K):
  // Xs fp32 [64][128] staged, then overwritten by Bsh(16K)+Bsl(16K).
  __shared__ __align__(16) char sm[65536];
  const int tid = threadIdx.x, l = tid & 63, w = tid >> 6;
  const int li = l & 15, g = l >> 4;
  const int lrow = l >> 3, lcol = (l & 7) * 8, wr = w >> 1, wc = w & 1;
  const int tp = tid >> 1;           // transpose role: p-column 0..127
  const int tch = (tid & 1) * 32;    // transpose role: c-half base
  const f32x4 z = {0.f, 0.f, 0.f, 0.f};
  f32x4 acc[4][4];
#pragma unroll
  for (int i = 0; i < 4; ++i)
#pragma unroll
    for (int j = 0; j < 4; ++j) acc[i][j] = z;

  char* Xs  = sm + 32768;
  char* Bsh = sm + 32768;
  char* Bsl = sm + 49152;

  if (blockIdx.x < 128) {
    // ---------------- qk path
    const int id = blockIdx.x;
    const int n0 = (id & 7) * 128, bn = id >> 3;
    const float* xb = x + (size_t)bn * CCH * PP;
    bf16* Ash = (bf16*)sm;
    bf16* Asl = (bf16*)(sm + 16384);

    auto stage_x = [&](int kt) {
#pragma unroll
      for (int i = 0; i < 8; ++i) {
        const int s = i * 256 + w * 64 + l;
        const int row = s >> 5, col16 = s & 31;
        gload16(xb + (size_t)(kt + row) * PP + n0 + col16 * 4,
                Xs + (i * 256 + w * 64) * 16);
      }
    };
    stage_x(0);

    for (int kt = 0; kt < CCH; kt += 64) {
      // stage W(t) into A region (X(t) already in flight)
#pragma unroll
      for (int it = 0; it < 4; ++it) {
        const int chunk = w * 4 + it;
        const int ar = chunk * 8 + lrow;
        gload16(Whi + (size_t)ar * CCH + kt + lcol, &Ash[chunk * 512]);
        gload16(Wlo + (size_t)ar * CCH + kt + lcol, &Asl[chunk * 512]);
      }
      // X(t) landed block-wide (the 8 W loads, issued after, stay in flight)
      asm volatile("s_waitcnt vmcnt(8)" ::: "memory");
      __builtin_amdgcn_s_barrier();
      asm volatile("" ::: "memory");

      // transpose-convert: column tp, c-range [tch, tch+32) -> registers
      float f[32];
#pragma unroll
      for (int k = 0; k < 32; ++k)
        f[k] = *(const float*)(Xs + (size_t)(tch + k) * 512 + tp * 4);
      // col reads done (X region free) AND W(t) landed
      asm volatile("s_waitcnt vmcnt(0) lgkmcnt(0)" ::: "memory");
      __builtin_amdgcn_s_barrier();
      asm volatile("" ::: "memory");

#pragma unroll
      for (int k2 = 0; k2 < 4; ++k2) {
        bf16x8 hv, lv;
#pragma unroll
        for (int j = 0; j < 8; ++j) {
          const float ff = f[k2 * 8 + j];
          const bf16 h = f2bf(ff);
          const bf16 lo_ = f2bf(ff - bf2f(h));
          short hs, ls;
          __builtin_memcpy(&hs, &h, 2);
          __builtin_memcpy(&ls, &lo_, 2);
          hv[j] = hs;
          lv[j] = ls;
        }
        const int chunk = (tch >> 3) + k2;
        const int pu = chunk ^ (tp & 7);
        *(bf16x8*)(Bsh + tp * 128 + pu * 16) = hv;
        *(bf16x8*)(Bsl + tp * 128 + pu * 16) = lv;
      }
      barrier_lgkm0();  // B tiles visible

      // pre-read ALL B fragments (both kk) -> registers
      bf16x8 bh[2][4], bl[2][4];
#pragma unroll
      for (int kk = 0; kk < 2; ++kk)
#pragma unroll
        for (int j = 0; j < 4; ++j) {
          const int row = wc * 64 + j * 16 + li;
          const int pu = (4 * kk + g) ^ (row & 7);
          bh[kk][j] = *(const bf16x8*)(Bsh + row * 128 + pu * 16);
          bl[kk][j] = *(const bf16x8*)(Bsl + row * 128 + pu * 16);
        }
      barrier_lgkm0();  // B reads done everywhere; X region free

      if (kt + 64 < CCH) stage_x(kt + 64);  // prefetch, hidden under MFMA

#pragma unroll
      for (int kk = 0; kk < 2; ++kk) {
        bf16x8 ah[4], al[4];
        const int ko = kk * 32 + g * 8;
#pragma unroll
        for (int i = 0; i < 4; ++i) {
          const int r = (wr * 64 + i * 16 + li) * 64 + ko;
          ah[i] = *(const bf16x8*)&Ash[r];
          al[i] = *(const bf16x8*)&Asl[r];
        }
#pragma unroll
        for (int i = 0; i < 4; ++i)
#pragma unroll
          for (int j = 0; j < 4; ++j) {
            acc[i][j] = __builtin_amdgcn_mfma_f32_16x16x32_bf16(ah[i], bh[kk][j], acc[i][j], 0, 0, 0);
            acc[i][j] = __builtin_amdgcn_mfma_f32_16x16x32_bf16(ah[i], bl[kk][j], acc[i][j], 0, 0, 0);
            acc[i][j] = __builtin_amdgcn_mfma_f32_16x16x32_bf16(al[i], bh[kk][j], acc[i][j], 0, 0, 0);
          }
      }
      // A-frag reads consumed by own MFMA; next step's W staging is safe
      asm volatile("" ::: "memory");
      __builtin_amdgcn_s_barrier();
      asm volatile("" ::: "memory");
    }
    const size_t qoff = (size_t)bn * PP * OCH;
#pragma unroll
    for (int i = 0; i < 4; ++i)
#pragma unroll
      for (int j = 0; j < 4; ++j)
#pragma unroll
        for (int r = 0; r < 4; ++r) {
          const int m = wr * 64 + i * 16 + g * 4 + r;
          const int p = n0 + wc * 64 + j * 16 + li;
          const float v = acc[i][j][r] + biasqk[m];
          const bf16 hi = f2bf(v);
          const bf16 lo = f2bf(v - bf2f(hi));
          if (m < 64) {
            qhi[qoff + (size_t)p * OCH + m] = hi;
            qlo[qoff + (size_t)p * OCH + m] = lo;
          } else {
            khi[qoff + (size_t)p * OCH + (m - 64)] = hi;
            klo[qoff + (size_t)p * OCH + (m - 64)] = lo;
          }
        }
  } else {
    // ---------------- v path (hi-only B), M=128, same pipeline
    const int id = blockIdx.x - 128;
    const int n0 = (id & 7) * 128, m0 = ((id >> 3) & 3) * 128, bn = id >> 5;
    const float* xb = x + (size_t)bn * CCH * PP;
    bf16* As = (bf16*)sm;

    auto stage_x = [&](int kt) {
#pragma unroll
      for (int i = 0; i < 8; ++i) {
        const int s = i * 256 + w * 64 + l;
        const int row = s >> 5, col16 = s & 31;
        gload16(xb + (size_t)(kt + row) * PP + n0 + col16 * 4,
                Xs + (i * 256 + w * 64) * 16);
      }
    };
    stage_x(0);

    for (int kt = 0; kt < CCH; kt += 64) {
#pragma unroll
      for (int it = 0; it < 4; ++it) {
        const int chunk = w * 4 + it;
        gload16(Wv + (size_t)(m0 + chunk * 8 + lrow) * CCH + kt + lcol, &As[chunk * 512]);
      }
      asm volatile("s_waitcnt vmcnt(4)" ::: "memory");
      __builtin_amdgcn_s_barrier();
      asm volatile("" ::: "memory");

      float f[32];
#pragma unroll
      for (int k = 0; k < 32; ++k)
        f[k] = *(const float*)(Xs + (size_t)(tch + k) * 512 + tp * 4);
      asm volatile("s_waitcnt vmcnt(0) lgkmcnt(0)" ::: "memory");
      __builtin_amdgcn_s_barrier();
      asm volatile("" ::: "memory");

#pragma unroll
      for (int k2 = 0; k2 < 4; ++k2) {
        bf16x8 hv;
#pragma unroll
        for (int j = 0; j < 8; ++j) {
          const bf16 h = f2bf(f[k2 * 8 + j]);
          short hs;
          __builtin_memcpy(&hs, &h, 2);
          hv[j] = hs;
        }
        const int chunk = (tch >> 3) + k2;
        const int pu = chunk ^ (tp & 7);
        *(bf16x8*)(Bsh + tp * 128 + pu * 16) = hv;
      }
      barrier_lgkm0();

      bf16x8 b[2][4];
#pragma unroll
      for (int kk = 0; kk < 2; ++kk)
#pragma unroll
        for (int j = 0; j < 4; ++j) {
          const int row = wc * 64 + j * 16 + li;
          const int pu = (4 * kk + g) ^ (row & 7);
          b[kk][j] = *(const bf16x8*)(Bsh + row * 128 + pu * 16);
        }
      barrier_lgkm0();

      if (kt + 64 < CCH) stage_x(kt + 64);

#pragma unroll
      for (int kk = 0; kk < 2; ++kk) {
        bf16x8 a[4];
        const int ko = kk * 32 + g * 8;
#pragma unroll
        for (int i = 0; i < 4; ++i)
          a[i] = *(const bf16x8*)&As[(wr * 64 + i * 16 + li) * 64 + ko];
#pragma unroll
        for (int i = 0; i < 4; ++i)
#pragma unroll
          for (int j = 0; j < 4; ++j)
            acc[i][j] = __builtin_amdgcn_mfma_f32_16x16x32_bf16(a[i], b[kk][j], acc[i][j], 0, 0, 0);
      }
      asm volatile("" ::: "memory");
      __builtin_amdgcn_s_barrier();
      asm volatile("" ::: "memory");
    }
#pragma unroll
    for (int i = 0; i < 4; ++i)
#pragma unroll
      for (int j = 0; j < 4; ++j)
#pragma unroll
        for (int r = 0; r < 4; ++r) {
          const int m = m0 + wr * 64 + i * 16 + g * 4 + r;
          const int p = n0 + wc * 64 + j * 16 + li;
          Vout[(size_t)bn * CCH * PP + (size_t)m * PP + p] = f2bf(acc[i][j][r] + biasv[m]);
        }
  }
}

// ---------------------------------------------------- fused flash attention + epilogue
// R7/R13 structure FROZEN (best measured). Unchanged.
#define KT 32
#define NT 32

__global__ __launch_bounds__(512, 2) void fused_attn_kernel(
    const bf16* __restrict__ qhi, const bf16* __restrict__ qlo,
    const bf16* __restrict__ khi, const bf16* __restrict__ klo,
    const bf16* __restrict__ vbuf, const float* __restrict__ tensor,
    const float* __restrict__ gamma, float* __restrict__ out) {
  __shared__ __align__(16) char smem[102400];
  __shared__ float red[128];
  __shared__ float fq[64];
  const int tid = threadIdx.x, l = tid & 63, w = tid >> 6;

  const int d = blockIdx.x;
  const int idx = d >> 3;
  const int bn = (d & 7) * 2 + (idx >> 4);
  const int qt0 = (idx & 15) * 64;

  const size_t qkoff = (size_t)bn * PP * OCH;
  const size_t voff  = (size_t)bn * CCH * PP;
  char* Qh = smem;
  char* Ql = smem + 8192;
  char* Pb = smem + 98304;

  {
    const int s = (w << 6) | l;
    const int row = s >> 3, pu = s & 7, lu = pu ^ (row & 7);
    const size_t src = qkoff + (size_t)(qt0 + row) * OCH + lu * 8;
    gload16(qhi + src, Qh + w * 1024);
    gload16(qlo + src, Ql + w * 1024);
  }
  barrier_vm0();

  bf16x8 ah[2], al[2];
  {
    const int qrow = ((w & 3) << 4) + (l & 15);
#pragma unroll
    for (int h = 0; h < 2; ++h) {
      const int lu = (l >> 4) + 4 * h, pu = lu ^ (qrow & 7);
      ah[h] = *(const bf16x8*)(Qh + qrow * 128 + pu * 16);
      al[h] = *(const bf16x8*)(Ql + qrow * 128 + pu * 16);
    }
  }

  auto stage_kv = [&](int t, char* khD, char* klD, char* vD) {
    {
      const int s = ((w & 3) << 6) | l;
      const int row = s >> 3, pu = s & 7, lu = pu ^ (row & 7);
      const bf16* srcp = ((w < 4) ? khi : klo) + qkoff + (size_t)(t * KT + row) * OCH + lu * 8;
      gload16(srcp, ((w < 4) ? khD : klD) + (w & 3) * 1024);
    }
#pragma unroll
    for (int c4 = 0; c4 < 4; ++c4) {
      const int s = (w << 8) + (c4 << 6) + l;
      const int row = s >> 2, pu = s & 3, lu = pu ^ ((row >> 1) & 3);
      const bf16* srcp = vbuf + voff + (size_t)row * PP + t * KT + lu * 8;
      gload16(srcp, vD + ((w << 8) + (c4 << 6)) * 16);
    }
  };

  stage_kv(0, smem + 16384, smem + 24576, smem + 32768);

  f32x4 acc[4][4];
  const f32x4 z = {0.f, 0.f, 0.f, 0.f};
#pragma unroll
  for (int i = 0; i < 4; ++i)
#pragma unroll
    for (int j = 0; j < 4; ++j) acc[i][j] = z;
  float psum[4] = {0.f, 0.f, 0.f, 0.f};
  const int kf = w >> 2;

  for (int t = 0; t < NT; ++t) {
    char* khB = smem + 16384 + ((t & 1) ? 4096 : 0);
    char* klB = smem + 24576 + ((t & 1) ? 4096 : 0);
    char* vB  = smem + 32768 + ((t & 1) ? 32768 : 0);

    barrier_vm0();

    if (t + 1 < NT) {
      stage_kv(t + 1,
               smem + 16384 + ((t & 1) ? 0 : 4096),
               smem + 24576 + ((t & 1) ? 0 : 4096),
               smem + 32768 + ((t & 1) ? 0 : 32768));
    }

    bf16x8 kh_[2], kl_[2];
    const int krow = (kf << 4) + (l & 15);
#pragma unroll
    for (int h = 0; h < 2; ++h) {
      const int lu = (l >> 4) + 4 * h, pu = lu ^ (krow & 7);
      kh_[h] = *(const bf16x8*)(khB + krow * 128 + pu * 16);
      kl_[h] = *(const bf16x8*)(klB + krow * 128 + pu * 16);
    }
    __builtin_amdgcn_s_setprio(1);
    f32x4 s = z;
    s = __builtin_amdgcn_mfma_f32_16x16x32_bf16(ah[0], kh_[0], s, 0, 0, 0);
    s = __builtin_amdgcn_mfma_f32_16x16x32_bf16(ah[1], kh_[1], s, 0, 0, 0);
    s = __builtin_amdgcn_mfma_f32_16x16x32_bf16(al[0], kh_[0], s, 0, 0, 0);
    s = __builtin_amdgcn_mfma_f32_16x16x32_bf16(al[1], kh_[1], s, 0, 0, 0);
    s = __builtin_amdgcn_mfma_f32_16x16x32_bf16(ah[0], kl_[0], s, 0, 0, 0);
    s = __builtin_amdgcn_mfma_f32_16x16x32_bf16(ah[1], kl_[1], s, 0, 0, 0);
    __builtin_amdgcn_s_setprio(0);

#pragma unroll
    for (int r = 0; r < 4; ++r) {
      const float pv = __expf(s[r] - 30.f);
      const bf16 pb16 = f2bf(pv);
      psum[r] += bf2f(pb16);
      const int q = ((w & 3) << 4) + ((l >> 4) << 2) + r;
      const int k = (kf << 4) + (l & 15);
      const int pu = (k >> 3) ^ ((q >> 1) & 3);
      *(bf16*)(Pb + q * 64 + pu * 16 + (k & 7) * 2) = pb16;
    }
    barrier_lgkm0();

    bf16x8 va[4], pb[4];
#pragma unroll
    for (int i = 0; i < 4; ++i) {
      const int crow = (w << 6) + (i << 4) + (l & 15);
      const int pu = (l >> 4) ^ ((crow >> 1) & 3);
      va[i] = *(const bf16x8*)(vB + crow * 64 + pu * 16);
    }
#pragma unroll
    for (int j = 0; j < 4; ++j) {
      const int prow = (j << 4) + (l & 15);
      const int pu = (l >> 4) ^ ((prow >> 1) & 3);
      pb[j] = *(const bf16x8*)(Pb + prow * 64 + pu * 16);
    }
    __builtin_amdgcn_s_setprio(1);
#pragma unroll
    for (int i = 0; i < 4; ++i)
#pragma unroll
      for (int j = 0; j < 4; ++j)
        acc[i][j] = __builtin_amdgcn_mfma_f32_16x16x32_bf16(va[i], pb[j], acc[i][j], 0, 0, 0);
    __builtin_amdgcn_s_setprio(0);
  }

  f32x4 tv0[8];
#pragma unroll
  for (int it = 0; it < 8; ++it) {
    const int chunk = it * 512 + tid;
    const int cl = chunk >> 4, ch = chunk & 15;
    tv0[it] = *(const f32x4*)&tensor[((size_t)bn * CCH + cl) * PP + qt0 + ch * 4];
  }

#pragma unroll
  for (int off = 1; off < 16; off <<= 1)
#pragma unroll
    for (int r = 0; r < 4; ++r) psum[r] += __shfl_xor(psum[r], off);
  if ((l & 15) == 0) {
#pragma unroll
    for (int r = 0; r < 4; ++r) {
      const int q = ((w & 3) << 4) + ((l >> 4) << 2) + r;
      red[q * 2 + kf] = psum[r];
    }
  }
  __syncthreads();
  if (tid < 64) fq[tid] = gamma[0] / (red[tid * 2] + red[tid * 2 + 1]);
  __syncthreads();

  float* rep = (float*)smem;
  for (int half = 0; half < 2; ++half) {
    if ((w >> 2) == half) {
#pragma unroll
      for (int i = 0; i < 4; ++i)
#pragma unroll
        for (int j = 0; j < 4; ++j) {
          const int q = (j << 4) + (l & 15);
          const float f = fq[q];
          const int c0 = ((w & 3) << 6) + (i << 4) + ((l >> 4) << 2);
#pragma unroll
          for (int r = 0; r < 4; ++r) rep[(c0 + r) * 68 + q] = acc[i][j][r] * f;
        }
    }
    __syncthreads();
#pragma unroll
    for (int it = 0; it < 8; ++it) {
      const int chunk = it * 512 + tid;
      const int cl = chunk >> 4, ch = chunk & 15;
      const size_t gi = ((size_t)bn * CCH + half * 256 + cl) * PP + qt0 + ch * 4;
      const f32x4 tv = (half == 0) ? tv0[it] : *(const f32x4*)&tensor[gi];
      const f32x4 rv = *(const f32x4*)&rep[cl * 68 + ch * 4];
      *(f32x4*)&out[gi] = tv + rv;
    }
    __syncthreads();
  }
}

// -------------------------------------------------------------------- launcher
extern "C" void kernel_launch(void* const* d_in, const int* in_sizes, int n_in,
                              void* d_out, int out_size, void* d_ws, size_t ws_size,
                              hipStream_t stream) {
  const float* tensor  = (const float*)d_in[0];
  const float* key_w   = (const float*)d_in[1];
  const float* key_b   = (const float*)d_in[2];
  const float* query_w = (const float*)d_in[3];
  const float* query_b = (const float*)d_in[4];
  const float* value_w = (const float*)d_in[5];
  const float* value_b = (const float*)d_in[6];
  const float* gamma   = (const float*)d_in[7];

  char* ws = (char*)d_ws;
  size_t off = 0;
  auto alloc = [&](size_t bytes) -> char* {
    char* p = ws + off;
    off += (bytes + 255) & ~(size_t)255;
    return p;
  };
  bf16* wqk_hi = (bf16*)alloc(128 * 512 * 2);
  bf16* wqk_lo = (bf16*)alloc(128 * 512 * 2);
  bf16* wv     = (bf16*)alloc(512 * 512 * 2);
  float* bias_qk = (float*)alloc(128 * 4);
  float* bias_v  = (float*)alloc(512 * 4);
  bf16* q_hi = (bf16*)alloc((size_t)NBATCH * PP * OCH * 2);
  bf16* q_lo = (bf16*)alloc((size_t)NBATCH * PP * OCH * 2);
  bf16* k_hi = (bf16*)alloc((size_t)NBATCH * PP * OCH * 2);
  bf16* k_lo = (bf16*)alloc((size_t)NBATCH * PP * OCH * 2);
  bf16* vbuf = (bf16*)alloc((size_t)NBATCH * CCH * PP * 2);
  (void)ws_size; (void)in_sizes; (void)n_in; (void)out_size;

  prep_kernel<<<dim3(1283), dim3(256), 0, stream>>>(
      key_w, key_b, query_w, query_b, value_w, value_b,
      wqk_hi, wqk_lo, wv, bias_qk, bias_v);

  gemm_qkv_kernel<<<dim3(640), dim3(256), 0, stream>>>(
      wqk_hi, wqk_lo, wv, tensor, bias_qk, bias_v,
      q_hi, q_lo, k_hi, k_lo, vbuf);

  fused_attn_kernel<<<dim3(256), dim3(512), 0, stream>>>(
      q_hi, q_lo, k_hi, k_lo, vbuf, tensor, gamma, (float*)d_out);
}